// Round 10
// baseline (1569.146 us; speedup 1.0000x reference)
//
#include <hip/hip_runtime.h>
#include <hip/hip_bf16.h>

// ---------------------------------------------------------------------------
// 3-layer GAT forward (PyG GATConv, eval) on MI355X.
// Round 10 delta vs r7 (best known): CSR is keyed by (dst, src>>11) so each
// dst's edge list is CLUSTERED BY SOURCE BLOCK (15 blocks x <=2048 src rows
// ~ 1.8MB of fp16 h~ each, fits one XCD L2). Co-resident waves walk blocks
// in the same order -> gather window is L2-sized instead of 23MB.
// Everything else identical: split-bf16 MFMA GEMM -> fp16 h~ -> fused agg
// (inline exp weights, 8ch/lane, 4-edge ILP, split-bf16 write, fused
// next-layer alpha projection).
// ---------------------------------------------------------------------------

#define NFEAT 129
#define MPAD  30080   // 235 * 128
#define BLKSH 11      // src block = src >> 11  (15 blocks for 30000)
#define KPD   16      // key slots per dst (>= 15)

typedef __attribute__((ext_vector_type(8))) short short8v;
typedef __attribute__((ext_vector_type(8))) unsigned short u16x8;
typedef __attribute__((ext_vector_type(8))) __bf16 bf16x8;
typedef __attribute__((ext_vector_type(4))) float f32x4;
typedef unsigned short u16;

union FragU { short8v s; bf16x8 b; };

__device__ inline u16 f2bf(float x) {
    unsigned u = __builtin_bit_cast(unsigned, x);
    unsigned r = (u + 0x7fffu + ((u >> 16) & 1u)) >> 16;
    return (u16)r;
}
__device__ inline float bf2f(u16 b) {
    unsigned u = ((unsigned)b) << 16;
    return __builtin_bit_cast(float, u);
}
__device__ inline float h2f(u16 u) { return (float)__builtin_bit_cast(_Float16, u); }
__device__ inline u16 f2h(float v) { return __builtin_bit_cast(u16, (_Float16)v); }

// ---------------- CSR build (keyed by dst*KPD + src-block) ----------------

__global__ __launch_bounds__(256) void hist_k(const int* __restrict__ src,
                                              const int* __restrict__ dst,
                                              int* __restrict__ cnt, int E, int n) {
    int e = blockIdx.x * 256 + threadIdx.x;
    if (e < E + n) {
        int s, d;
        if (e < E) { s = src[e]; d = dst[e]; }
        else       { s = d = e - E; }
        atomicAdd(&cnt[d * KPD + (s >> BLKSH)], 1);
    }
}

__global__ __launch_bounds__(1024) void scan_k(const int* __restrict__ cnt, int* __restrict__ row_ptr, int n) {
    __shared__ int part[1024];
    int tid = threadIdx.x;
    int per = (n + 1023) >> 10;
    int base = tid * per;
    int s = 0;
    for (int j = 0; j < per; ++j) {
        int idx = base + j;
        if (idx < n) s += cnt[idx];
    }
    part[tid] = s;
    __syncthreads();
    for (int off = 1; off < 1024; off <<= 1) {
        int v = 0;
        if (tid >= off) v = part[tid - off];
        __syncthreads();
        if (tid >= off) part[tid] += v;
        __syncthreads();
    }
    int run = (tid > 0) ? part[tid - 1] : 0;
    for (int j = 0; j < per; ++j) {
        int idx = base + j;
        if (idx < n) { row_ptr[idx] = run; run += cnt[idx]; }
    }
    if (tid == 0) row_ptr[n] = part[1023];
}

__global__ __launch_bounds__(256) void scatter_k(const int* __restrict__ src, const int* __restrict__ dst,
                                                 const int* __restrict__ row_ptr, int* __restrict__ fill,
                                                 int* __restrict__ col, int E, int n) {
    int e = blockIdx.x * 256 + threadIdx.x;
    if (e < E + n) {
        int s, d;
        if (e < E) { s = src[e]; d = dst[e]; }
        else       { s = d = e - E; }
        int key = d * KPD + (s >> BLKSH);
        int pos = row_ptr[key] + atomicAdd(&fill[key], 1);
        col[pos] = s;
    }
}

// ---------------- input split (fp32 -> bf16 hi/lo), row+K padded -----------

__global__ __launch_bounds__(256) void xsplit_k(const float* __restrict__ in,
                                                u16* __restrict__ hi, u16* __restrict__ lo,
                                                int Nn, int K, int Kp, int Mp) {
    int idx = blockIdx.x * 256 + threadIdx.x;
    if (idx >= Mp * Kp) return;
    int m = idx / Kp, k = idx - m * Kp;
    float v = (m < Nn && k < K) ? in[(size_t)m * K + k] : 0.f;
    u16 h = f2bf(v);
    hi[idx] = h;
    lo[idx] = f2bf(v - bf2f(h));
}

// ---------------- all three W splits (transposed, padded) in one kernel ----
// seg1 W1t: [512 x 160] K=129 N=448 @ 0
// seg2 W2t: [384 x 448] K=448 N=384 @ 81920
// seg3 W3t: [256 x 384] K=384 N=240 @ 253952   (total 352256)

__global__ __launch_bounds__(256) void wsplitAll_k(const float* __restrict__ W1,
                                                   const float* __restrict__ W2,
                                                   const float* __restrict__ W3,
                                                   u16* __restrict__ hi, u16* __restrict__ lo) {
    int idx = blockIdx.x * 256 + threadIdx.x;
    if (idx >= 352256) return;
    const float* W; int loc, Kp, K, N;
    if (idx < 81920)       { W = W1; loc = idx;          Kp = 160; K = 129; N = 448; }
    else if (idx < 253952) { W = W2; loc = idx - 81920;  Kp = 448; K = 448; N = 384; }
    else                   { W = W3; loc = idx - 253952; Kp = 384; K = 384; N = 240; }
    int nn = loc / Kp, k = loc - nn * Kp;
    float v = (k < K && nn < N) ? W[(size_t)k * N + nn] : 0.f;
    u16 h = f2bf(v);
    hi[idx] = h;
    lo[idx] = f2bf(v - bf2f(h));
}

// ---------------- all projection tables P[k][h]=sum_c W[k,h*C+c]*a[h][c] ---
// P1 rows [0,160) (K=129), P2 rows [160,608) (K=448), P3 rows [608,992).

__global__ __launch_bounds__(256) void projAll_k(
    const float* __restrict__ W1, const float* __restrict__ a1s, const float* __restrict__ a1d,
    const float* __restrict__ W2, const float* __restrict__ a2s, const float* __restrict__ a2d,
    const float* __restrict__ W3, const float* __restrict__ a3s, const float* __restrict__ a3d,
    float* __restrict__ Ps, float* __restrict__ Pd) {
    int idx = blockIdx.x * 256 + threadIdx.x;
    if (idx >= 992 * 8) return;
    int row = idx >> 3, h = idx & 7;
    const float *W, *as_, *ad_; int k, K, Ncols, H, C;
    if (row < 160)      { k = row;       K = 129; W = W1; as_ = a1s; ad_ = a1d; Ncols = 448; H = 7; C = 64; }
    else if (row < 608) { k = row - 160; K = 448; W = W2; as_ = a2s; ad_ = a2d; Ncols = 384; H = 6; C = 64; }
    else                { k = row - 608; K = 384; W = W3; as_ = a3s; ad_ = a3d; Ncols = 240; H = 6; C = 40; }
    float ps = 0.f, pd = 0.f;
    if (h < H && k < K) {
        const float* wr = W + (size_t)k * Ncols + h * C;
        const float* ar = as_ + h * C;
        const float* dr = ad_ + h * C;
        for (int c = 0; c < C; ++c) {
            float wv = wr[c];
            ps += wv * ar[c];
            pd += wv * dr[c];
        }
    }
    Ps[idx] = ps;
    Pd[idx] = pd;
}

// ---------------- zero h1 split pad rows (read as GEMM2 A-operand) ---------

__global__ __launch_bounds__(256) void zeropads_k(u16* __restrict__ h1hi, u16* __restrict__ h1lo,
                                                  int Nn) {
    int tot = (MPAD - Nn) * 448;
    int idx = blockIdx.x * 256 + threadIdx.x;
    if (idx < tot) {
        h1hi[(size_t)Nn * 448 + idx] = 0;
        h1lo[(size_t)Nn * 448 + idx] = 0;
    }
}

// ---------------- layer-1 alphas: (x @ P1), K=129, wave per node -----------

__global__ __launch_bounds__(256) void alpha1_k(const float* __restrict__ x,
                                                const float* __restrict__ Ps,
                                                const float* __restrict__ Pd,
                                                float* __restrict__ oS, float* __restrict__ oD, int n) {
    int wv = threadIdx.x >> 6, lane = threadIdx.x & 63;
    int i = blockIdx.x * 4 + wv;
    if (i >= n) return;
    const float* row = x + (size_t)i * NFEAT;
    float x0 = row[lane], x1 = row[64 + lane];
    float ps[8], pd[8];
    #pragma unroll
    for (int h = 0; h < 8; ++h) {
        ps[h] = x0 * Ps[lane * 8 + h] + x1 * Ps[(64 + lane) * 8 + h];
        pd[h] = x0 * Pd[lane * 8 + h] + x1 * Pd[(64 + lane) * 8 + h];
    }
    if (lane == 0) {
        float x2 = row[128];
        #pragma unroll
        for (int h = 0; h < 8; ++h) {
            ps[h] += x2 * Ps[128 * 8 + h];
            pd[h] += x2 * Pd[128 * 8 + h];
        }
    }
    #pragma unroll
    for (int h = 0; h < 8; ++h) {
        #pragma unroll
        for (int off = 32; off; off >>= 1) {
            ps[h] += __shfl_xor(ps[h], off);
            pd[h] += __shfl_xor(pd[h], off);
        }
    }
    if (lane == 0) {
        #pragma unroll
        for (int h = 0; h < 8; ++h) {
            oS[(size_t)i * 8 + h] = ps[h];
            oD[(size_t)i * 8 + h] = pd[h];
        }
    }
}

// ---------------- LDS swizzle helper ----------------

__device__ __forceinline__ int swz(int r, int s) {
    return (r << 2) | ((s ^ (r & 3) ^ ((r >> 2) & 3)) & 3);
}

// ---------------- split MFMA GEMM, fp16 output: C16 = A @ Wt^T -------------
// Tile 128x128, BK=32, 4 waves (2m x 2n), 3 MFMAs per hi/lo pair.

__global__ __launch_bounds__(256) void gemm16(
    const u16* __restrict__ Ahi, const u16* __restrict__ Alo,
    const u16* __restrict__ Bhi, const u16* __restrict__ Blo,
    u16* __restrict__ C16, int M, int Ncols, int Kp)
{
    __shared__ __align__(16) u16 sAh[128 * 32];
    __shared__ __align__(16) u16 sAl[128 * 32];
    __shared__ __align__(16) u16 sBh[128 * 32];
    __shared__ __align__(16) u16 sBl[128 * 32];
    const int tid = threadIdx.x;
    const int m0 = blockIdx.y * 128;
    const int n0 = blockIdx.x * 128;
    const int lane = tid & 63, wave = tid >> 6;
    const int wm = wave >> 1, wn = wave & 1;
    const int l15 = lane & 15, lg = lane >> 4;
    const int r0 = tid >> 2, s0 = tid & 3;
    const int w0 = swz(r0, s0), w1 = swz(r0 + 64, s0);
    f32x4 acc[4][4] = {};

    for (int k0 = 0; k0 < Kp; k0 += 32) {
        size_t gA0 = (size_t)(m0 + r0) * Kp + k0 + s0 * 8;
        size_t gA1 = (size_t)(m0 + r0 + 64) * Kp + k0 + s0 * 8;
        size_t gB0 = (size_t)(n0 + r0) * Kp + k0 + s0 * 8;
        size_t gB1 = (size_t)(n0 + r0 + 64) * Kp + k0 + s0 * 8;
        short8v ah0 = *(const short8v*)(Ahi + gA0);
        short8v ah1 = *(const short8v*)(Ahi + gA1);
        short8v al0 = *(const short8v*)(Alo + gA0);
        short8v al1 = *(const short8v*)(Alo + gA1);
        short8v bh0 = *(const short8v*)(Bhi + gB0);
        short8v bh1 = *(const short8v*)(Bhi + gB1);
        short8v bl0 = *(const short8v*)(Blo + gB0);
        short8v bl1 = *(const short8v*)(Blo + gB1);
        __syncthreads();
        ((short8v*)sAh)[w0] = ah0; ((short8v*)sAh)[w1] = ah1;
        ((short8v*)sAl)[w0] = al0; ((short8v*)sAl)[w1] = al1;
        ((short8v*)sBh)[w0] = bh0; ((short8v*)sBh)[w1] = bh1;
        ((short8v*)sBl)[w0] = bl0; ((short8v*)sBl)[w1] = bl1;
        __syncthreads();
        FragU fah[4], fal[4], fbh[4], fbl[4];
        #pragma unroll
        for (int mf = 0; mf < 4; ++mf) {
            int rr = wm * 64 + mf * 16 + l15;
            int idx = swz(rr, lg);
            fah[mf].s = ((const short8v*)sAh)[idx];
            fal[mf].s = ((const short8v*)sAl)[idx];
        }
        #pragma unroll
        for (int nf = 0; nf < 4; ++nf) {
            int rr = wn * 64 + nf * 16 + l15;
            int idx = swz(rr, lg);
            fbh[nf].s = ((const short8v*)sBh)[idx];
            fbl[nf].s = ((const short8v*)sBl)[idx];
        }
        #pragma unroll
        for (int mf = 0; mf < 4; ++mf) {
            #pragma unroll
            for (int nf = 0; nf < 4; ++nf) {
                acc[mf][nf] = __builtin_amdgcn_mfma_f32_16x16x32_bf16(fah[mf].b, fbh[nf].b, acc[mf][nf], 0, 0, 0);
                acc[mf][nf] = __builtin_amdgcn_mfma_f32_16x16x32_bf16(fah[mf].b, fbl[nf].b, acc[mf][nf], 0, 0, 0);
                acc[mf][nf] = __builtin_amdgcn_mfma_f32_16x16x32_bf16(fal[mf].b, fbh[nf].b, acc[mf][nf], 0, 0, 0);
            }
        }
    }
    #pragma unroll
    for (int mf = 0; mf < 4; ++mf) {
        #pragma unroll
        for (int nf = 0; nf < 4; ++nf) {
            int colg = n0 + wn * 64 + nf * 16 + l15;
            if (colg >= Ncols) continue;
            #pragma unroll
            for (int r = 0; r < 4; ++r) {
                int rowg = m0 + wm * 64 + mf * 16 + lg * 4 + r;
                if (rowg < M) C16[(size_t)rowg * Ncols + colg] = f2h(acc[mf][nf][r]);
            }
        }
    }
}

// ---------------- fused agg: weights+denom inline, fp16 gather, proj epi ---
// wave per node; lane owns 8 consecutive channels (16B fp16 load/edge);
// 4 edges in flight; edges arrive CLUSTERED BY SRC BLOCK (CSR key order).

template <int H, int C, bool RELU, bool SPLIT, bool PROJ>
__global__ __launch_bounds__(256) void aggF_k(
    const u16* __restrict__ hf,                                  // fp16 h~ [n][HC]
    const float* __restrict__ as_, const float* __restrict__ ad_,
    const float* __restrict__ bias,
    const int* __restrict__ row_ptr,                             // keyed: [n*KPD+1]
    const int* __restrict__ col,
    const float* __restrict__ Pns, const float* __restrict__ Pnd, // next-layer proj [HC][8]
    float* __restrict__ nas, float* __restrict__ nad,             // next-layer alphas
    float* __restrict__ outf, u16* __restrict__ ohi, u16* __restrict__ olo,
    int n)
{
    constexpr int HC = H * C;
    constexpr int LACT = HC / 8;
    const int wv = threadIdx.x >> 6, lane = threadIdx.x & 63;
    const int i = blockIdx.x * 4 + wv;
    if (i >= n) return;
    const int ch0 = lane * 8;
    const bool act = lane < LACT;
    const int h = act ? (ch0 / C) : 0;
    const bool lead = act && ((ch0 % C) == 0);
    const int beg = row_ptr[i * KPD], end = row_ptr[(i + 1) * KPD];
    float acc[8] = {};
    float dp = 0.f;
    if (act) {
        const float adh = ad_[(size_t)i * 8 + h];
        int e = beg;
        for (; e + 4 <= end; e += 4) {
            int sA = col[e],     sB = col[e + 1];
            int sC = col[e + 2], sD = col[e + 3];
            float fA = as_[(size_t)sA * 8 + h] + adh;
            float fB = as_[(size_t)sB * 8 + h] + adh;
            float fC = as_[(size_t)sC * 8 + h] + adh;
            float fD = as_[(size_t)sD * 8 + h] + adh;
            u16x8 vA = *(const u16x8*)(hf + (size_t)sA * HC + ch0);
            u16x8 vB = *(const u16x8*)(hf + (size_t)sB * HC + ch0);
            u16x8 vC = *(const u16x8*)(hf + (size_t)sC * HC + ch0);
            u16x8 vD = *(const u16x8*)(hf + (size_t)sD * HC + ch0);
            fA = fA > 0.f ? fA : 0.2f * fA;
            fB = fB > 0.f ? fB : 0.2f * fB;
            fC = fC > 0.f ? fC : 0.2f * fC;
            fD = fD > 0.f ? fD : 0.2f * fD;
            float wA = __expf(fA), wB = __expf(fB);
            float wC = __expf(fC), wD = __expf(fD);
            #pragma unroll
            for (int j = 0; j < 8; ++j)
                acc[j] += wA * h2f(vA[j]) + wB * h2f(vB[j])
                        + wC * h2f(vC[j]) + wD * h2f(vD[j]);
            if (lead) dp += (wA + wB) + (wC + wD);
        }
        for (; e + 2 <= end; e += 2) {
            int sA = col[e], sB = col[e + 1];
            float fA = as_[(size_t)sA * 8 + h] + adh;
            float fB = as_[(size_t)sB * 8 + h] + adh;
            u16x8 vA = *(const u16x8*)(hf + (size_t)sA * HC + ch0);
            u16x8 vB = *(const u16x8*)(hf + (size_t)sB * HC + ch0);
            fA = fA > 0.f ? fA : 0.2f * fA;
            fB = fB > 0.f ? fB : 0.2f * fB;
            float wA = __expf(fA), wB = __expf(fB);
            #pragma unroll
            for (int j = 0; j < 8; ++j)
                acc[j] += wA * h2f(vA[j]) + wB * h2f(vB[j]);
            if (lead) dp += wA + wB;
        }
        if (e < end) {
            int sA = col[e];
            float fA = as_[(size_t)sA * 8 + h] + adh;
            u16x8 vA = *(const u16x8*)(hf + (size_t)sA * HC + ch0);
            fA = fA > 0.f ? fA : 0.2f * fA;
            float wA = __expf(fA);
            #pragma unroll
            for (int j = 0; j < 8; ++j)
                acc[j] += wA * h2f(vA[j]);
            if (lead) dp += wA;
        }
    }
    const float den = __shfl(dp, h * (C / 8)) + 1e-16f;
    float o[8];
    #pragma unroll
    for (int j = 0; j < 8; ++j) o[j] = 0.f;
    if (act) {
        #pragma unroll
        for (int j = 0; j < 8; ++j) {
            float v = acc[j] / den + bias[ch0 + j];
            if (RELU) v = fmaxf(v, 0.f);
            o[j] = v;
        }
        size_t base = (size_t)i * HC + ch0;
        if constexpr (SPLIT) {
            u16x8 ph, pl;
            #pragma unroll
            for (int j = 0; j < 8; ++j) {
                u16 hi = f2bf(o[j]);
                ph[j] = hi;
                pl[j] = f2bf(o[j] - bf2f(hi));
            }
            *(u16x8*)(ohi + base) = ph;
            *(u16x8*)(olo + base) = pl;
        } else {
            float4 q0; q0.x = o[0]; q0.y = o[1]; q0.z = o[2]; q0.w = o[3];
            float4 q1; q1.x = o[4]; q1.y = o[5]; q1.z = o[6]; q1.w = o[7];
            *(float4*)(outf + base) = q0;
            *(float4*)(outf + base + 4) = q1;
        }
    }
    if constexpr (PROJ) {
        float ps[8] = {}, pd[8] = {};
        if (act) {
            #pragma unroll
            for (int j = 0; j < 8; ++j) {
                const float* prs = Pns + (size_t)(ch0 + j) * 8;
                const float* prd = Pnd + (size_t)(ch0 + j) * 8;
                #pragma unroll
                for (int hp = 0; hp < 8; ++hp) {
                    ps[hp] += o[j] * prs[hp];
                    pd[hp] += o[j] * prd[hp];
                }
            }
        }
        #pragma unroll
        for (int hp = 0; hp < 8; ++hp) {
            #pragma unroll
            for (int off = 32; off; off >>= 1) {
                ps[hp] += __shfl_xor(ps[hp], off);
                pd[hp] += __shfl_xor(pd[hp], off);
            }
        }
        if (lane == 0) {
            #pragma unroll
            for (int hp = 0; hp < 8; ++hp) {
                nas[(size_t)i * 8 + hp] = ps[hp];
                nad[(size_t)i * 8 + hp] = pd[hp];
            }
        }
    }
}

// ---------------------------------------------------------------------------

extern "C" void kernel_launch(void* const* d_in, const int* in_sizes, int n_in,
                              void* d_out, int out_size, void* d_ws, size_t ws_size,
                              hipStream_t stream) {
    const float* x   = (const float*)d_in[0];
    const int*   ei  = (const int*)d_in[1];
    const float* W1  = (const float*)d_in[2];
    const float* a1s = (const float*)d_in[3];
    const float* a1d = (const float*)d_in[4];
    const float* b1  = (const float*)d_in[5];
    const float* W2  = (const float*)d_in[6];
    const float* a2s = (const float*)d_in[7];
    const float* a2d = (const float*)d_in[8];
    const float* b2  = (const float*)d_in[9];
    const float* W3  = (const float*)d_in[10];
    const float* a3s = (const float*)d_in[11];
    const float* a3d = (const float*)d_in[12];
    const float* b3  = (const float*)d_in[13];
    float* out = (float*)d_out;

    const int Nn = in_sizes[0] / NFEAT;   // 30000
    const int E  = in_sizes[1] / 2;       // 480000
    const int Et = E + Nn;
    const int NK = Nn * KPD;              // 480000 keys
    const int* srcp = ei;
    const int* dstp = ei + E;

    char* ws = (char*)d_ws;
    size_t off = 0;
    auto carve = [&](size_t bytes) -> char* {
        char* p = ws + off;
        off += (bytes + 255) & ~(size_t)255;
        return p;
    };
    u16*   hbuf16 = (u16*)carve((size_t)MPAD * 448 * 2);   // h~ fp16 (all layers)
    u16*   h1hi  = (u16*)carve((size_t)MPAD * 448 * 2);    // h split
    u16*   h1lo  = (u16*)carve((size_t)MPAD * 448 * 2);
    u16*   Xhi   = (u16*)carve((size_t)MPAD * 160 * 2);
    u16*   Xlo   = (u16*)carve((size_t)MPAD * 160 * 2);
    u16*   Wthi  = (u16*)carve((size_t)352256 * 2);
    u16*   Wtlo  = (u16*)carve((size_t)352256 * 2);
    int*   col   = (int*)carve((size_t)Et * 4);
    int* row_ptr = (int*)carve((size_t)(NK + 1) * 4);
    int*   cnt   = (int*)carve((size_t)NK * 4);
    float* aA    = (float*)carve((size_t)Nn * 8 * 4);
    float* dA    = (float*)carve((size_t)Nn * 8 * 4);
    float* aB    = (float*)carve((size_t)Nn * 8 * 4);
    float* dB    = (float*)carve((size_t)Nn * 8 * 4);
    float* Ps    = (float*)carve((size_t)992 * 8 * 4);
    float* Pd    = (float*)carve((size_t)992 * 8 * 4);
    (void)ws_size;

    const int nb4 = (Nn + 3) / 4;   // 7500
    const int mg  = MPAD / 128;     // 235

    // ---- CSR keyed by (dst, src-block): edge lists come out block-clustered --
    hipMemsetAsync(cnt, 0, (size_t)NK * 4, stream);
    hist_k<<<(Et + 255) / 256, 256, 0, stream>>>(srcp, dstp, cnt, E, Nn);
    scan_k<<<1, 1024, 0, stream>>>(cnt, row_ptr, NK);
    hipMemsetAsync(cnt, 0, (size_t)NK * 4, stream);
    scatter_k<<<(Et + 255) / 256, 256, 0, stream>>>(srcp, dstp, row_ptr, cnt, col, E, Nn);

    // ---- input prep (independent of CSR) ----
    xsplit_k<<<((MPAD * 160) + 255) / 256, 256, 0, stream>>>(x, Xhi, Xlo, Nn, NFEAT, 160, MPAD);
    wsplitAll_k<<<(352256 + 255) / 256, 256, 0, stream>>>(W1, W2, W3, Wthi, Wtlo);
    projAll_k<<<(992 * 8 + 255) / 256, 256, 0, stream>>>(W1, a1s, a1d, W2, a2s, a2d, W3, a3s, a3d, Ps, Pd);
    zeropads_k<<<(((MPAD - Nn) * 448) + 255) / 256, 256, 0, stream>>>(h1hi, h1lo, Nn);

    // ---- layer 1: x(129) -> 7x64 ----
    alpha1_k<<<nb4, 256, 0, stream>>>(x, Ps, Pd, aA, dA, Nn);
    gemm16<<<dim3(4, mg), 256, 0, stream>>>(Xhi, Xlo, Wthi, Wtlo, hbuf16, Nn, 448, 160);
    aggF_k<7, 64, true, true, true><<<nb4, 256, 0, stream>>>(
        hbuf16, aA, dA, b1, row_ptr, col, Ps + 1280, Pd + 1280, aB, dB,
        nullptr, h1hi, h1lo, Nn);

    // ---- layer 2: 448 -> 6x64 ----
    gemm16<<<dim3(3, mg), 256, 0, stream>>>(h1hi, h1lo, Wthi + 81920, Wtlo + 81920, hbuf16, Nn, 384, 448);
    aggF_k<6, 64, true, true, true><<<nb4, 256, 0, stream>>>(
        hbuf16, aB, dB, b2, row_ptr, col, Ps + 4864, Pd + 4864, aA, dA,
        nullptr, h1hi, h1lo, Nn);

    // ---- layer 3: 384 -> 6x40 ----
    gemm16<<<dim3(2, mg), 256, 0, stream>>>(h1hi, h1lo, Wthi + 253952, Wtlo + 253952, hbuf16, Nn, 240, 384);
    aggF_k<6, 40, false, false, false><<<nb4, 256, 0, stream>>>(
        hbuf16, aA, dA, b3, row_ptr, col, nullptr, nullptr, nullptr, nullptr,
        out, nullptr, nullptr, Nn);
}

// Round 11
// 557.728 us; speedup vs baseline: 2.8135x; 2.8135x over previous
//
#include <hip/hip_runtime.h>
#include <hip/hip_bf16.h>

// ---------------------------------------------------------------------------
// 3-layer GAT forward (PyG GATConv, eval) on MI355X.
// CSR keyed by (dst, src>>11): each dst's edge list is clustered by source
// block (~1.8MB of fp16 h~ per block, L2-sized window for co-resident waves).
// Hierarchical 3-stage scan for the 480k-key row_ptr (r10's single-block
// scan was 1ms - pure plumbing bug).
// Pipeline per layer: split-bf16 MFMA GEMM -> fp16 h~ -> fused agg
// (inline exp weights, 8ch/lane, 4-edge ILP, split-bf16 write, fused
// next-layer alpha projection).
// ---------------------------------------------------------------------------

#define NFEAT 129
#define MPAD  30080   // 235 * 128
#define BLKSH 11      // src block = src >> 11  (15 blocks for 30000)
#define KPD   16      // key slots per dst (>= 15)

typedef __attribute__((ext_vector_type(8))) short short8v;
typedef __attribute__((ext_vector_type(8))) unsigned short u16x8;
typedef __attribute__((ext_vector_type(8))) __bf16 bf16x8;
typedef __attribute__((ext_vector_type(4))) float f32x4;
typedef unsigned short u16;

union FragU { short8v s; bf16x8 b; };

__device__ inline u16 f2bf(float x) {
    unsigned u = __builtin_bit_cast(unsigned, x);
    unsigned r = (u + 0x7fffu + ((u >> 16) & 1u)) >> 16;
    return (u16)r;
}
__device__ inline float bf2f(u16 b) {
    unsigned u = ((unsigned)b) << 16;
    return __builtin_bit_cast(float, u);
}
__device__ inline float h2f(u16 u) { return (float)__builtin_bit_cast(_Float16, u); }
__device__ inline u16 f2h(float v) { return __builtin_bit_cast(u16, (_Float16)v); }

// ---------------- CSR build (keyed by dst*KPD + src-block) ----------------

__global__ __launch_bounds__(256) void hist_k(const int* __restrict__ src,
                                              const int* __restrict__ dst,
                                              int* __restrict__ cnt, int E, int n) {
    int e = blockIdx.x * 256 + threadIdx.x;
    if (e < E + n) {
        int s, d;
        if (e < E) { s = src[e]; d = dst[e]; }
        else       { s = d = e - E; }
        atomicAdd(&cnt[d * KPD + (s >> BLKSH)], 1);
    }
}

// hierarchical scan: stage 1 — per-block (256) sums
__global__ __launch_bounds__(256) void bsum_k(const int* __restrict__ cnt,
                                              int* __restrict__ bsum, int nk) {
    __shared__ int sh[256];
    int t = threadIdx.x, idx = blockIdx.x * 256 + t;
    sh[t] = (idx < nk) ? cnt[idx] : 0;
    __syncthreads();
    for (int o = 128; o; o >>= 1) {
        if (t < o) sh[t] += sh[t + o];
        __syncthreads();
    }
    if (t == 0) bsum[blockIdx.x] = sh[0];
}

// stage 2 — single block exclusive-scans the <=2048 block sums
__global__ __launch_bounds__(1024) void bscan_k(const int* __restrict__ bsum,
                                                int* __restrict__ bofs, int nb) {
    __shared__ int part[1024];
    int t = threadIdx.x;
    int per = (nb + 1023) >> 10;
    int base = t * per;
    int s = 0;
    for (int j = 0; j < per; ++j) {
        int i = base + j;
        if (i < nb) s += bsum[i];
    }
    part[t] = s;
    __syncthreads();
    for (int o = 1; o < 1024; o <<= 1) {
        int v = 0;
        if (t >= o) v = part[t - o];
        __syncthreads();
        if (t >= o) part[t] += v;
        __syncthreads();
    }
    int run = (t > 0) ? part[t - 1] : 0;
    for (int j = 0; j < per; ++j) {
        int i = base + j;
        if (i < nb) { bofs[i] = run; run += bsum[i]; }
    }
    if (t == 1023) bofs[nb] = part[1023];
}

// stage 3 — local Hillis-Steele scan + block offset -> row_ptr
__global__ __launch_bounds__(256) void scanw_k(const int* __restrict__ cnt,
                                               const int* __restrict__ bofs,
                                               int* __restrict__ row_ptr, int nk) {
    __shared__ int sh[256];
    int t = threadIdx.x, idx = blockIdx.x * 256 + t;
    int v = (idx < nk) ? cnt[idx] : 0;
    sh[t] = v;
    __syncthreads();
    for (int o = 1; o < 256; o <<= 1) {
        int u = 0;
        if (t >= o) u = sh[t - o];
        __syncthreads();
        if (t >= o) sh[t] += u;
        __syncthreads();
    }
    if (idx < nk) row_ptr[idx] = bofs[blockIdx.x] + sh[t] - v;
    if (idx == nk - 1) row_ptr[nk] = bofs[blockIdx.x] + sh[t];
}

__global__ __launch_bounds__(256) void scatter_k(const int* __restrict__ src, const int* __restrict__ dst,
                                                 const int* __restrict__ row_ptr, int* __restrict__ fill,
                                                 int* __restrict__ col, int E, int n) {
    int e = blockIdx.x * 256 + threadIdx.x;
    if (e < E + n) {
        int s, d;
        if (e < E) { s = src[e]; d = dst[e]; }
        else       { s = d = e - E; }
        int key = d * KPD + (s >> BLKSH);
        int pos = row_ptr[key] + atomicAdd(&fill[key], 1);
        col[pos] = s;
    }
}

// ---------------- input split (fp32 -> bf16 hi/lo), row+K padded -----------

__global__ __launch_bounds__(256) void xsplit_k(const float* __restrict__ in,
                                                u16* __restrict__ hi, u16* __restrict__ lo,
                                                int Nn, int K, int Kp, int Mp) {
    int idx = blockIdx.x * 256 + threadIdx.x;
    if (idx >= Mp * Kp) return;
    int m = idx / Kp, k = idx - m * Kp;
    float v = (m < Nn && k < K) ? in[(size_t)m * K + k] : 0.f;
    u16 h = f2bf(v);
    hi[idx] = h;
    lo[idx] = f2bf(v - bf2f(h));
}

// ---------------- all three W splits (transposed, padded) in one kernel ----
// seg1 W1t: [512 x 160] K=129 N=448 @ 0
// seg2 W2t: [384 x 448] K=448 N=384 @ 81920
// seg3 W3t: [256 x 384] K=384 N=240 @ 253952   (total 352256)

__global__ __launch_bounds__(256) void wsplitAll_k(const float* __restrict__ W1,
                                                   const float* __restrict__ W2,
                                                   const float* __restrict__ W3,
                                                   u16* __restrict__ hi, u16* __restrict__ lo) {
    int idx = blockIdx.x * 256 + threadIdx.x;
    if (idx >= 352256) return;
    const float* W; int loc, Kp, K, N;
    if (idx < 81920)       { W = W1; loc = idx;          Kp = 160; K = 129; N = 448; }
    else if (idx < 253952) { W = W2; loc = idx - 81920;  Kp = 448; K = 448; N = 384; }
    else                   { W = W3; loc = idx - 253952; Kp = 384; K = 384; N = 240; }
    int nn = loc / Kp, k = loc - nn * Kp;
    float v = (k < K && nn < N) ? W[(size_t)k * N + nn] : 0.f;
    u16 h = f2bf(v);
    hi[idx] = h;
    lo[idx] = f2bf(v - bf2f(h));
}

// ---------------- all projection tables P[k][h]=sum_c W[k,h*C+c]*a[h][c] ---
// P1 rows [0,160) (K=129), P2 rows [160,608) (K=448), P3 rows [608,992).

__global__ __launch_bounds__(256) void projAll_k(
    const float* __restrict__ W1, const float* __restrict__ a1s, const float* __restrict__ a1d,
    const float* __restrict__ W2, const float* __restrict__ a2s, const float* __restrict__ a2d,
    const float* __restrict__ W3, const float* __restrict__ a3s, const float* __restrict__ a3d,
    float* __restrict__ Ps, float* __restrict__ Pd) {
    int idx = blockIdx.x * 256 + threadIdx.x;
    if (idx >= 992 * 8) return;
    int row = idx >> 3, h = idx & 7;
    const float *W, *as_, *ad_; int k, K, Ncols, H, C;
    if (row < 160)      { k = row;       K = 129; W = W1; as_ = a1s; ad_ = a1d; Ncols = 448; H = 7; C = 64; }
    else if (row < 608) { k = row - 160; K = 448; W = W2; as_ = a2s; ad_ = a2d; Ncols = 384; H = 6; C = 64; }
    else                { k = row - 608; K = 384; W = W3; as_ = a3s; ad_ = a3d; Ncols = 240; H = 6; C = 40; }
    float ps = 0.f, pd = 0.f;
    if (h < H && k < K) {
        const float* wr = W + (size_t)k * Ncols + h * C;
        const float* ar = as_ + h * C;
        const float* dr = ad_ + h * C;
        for (int c = 0; c < C; ++c) {
            float wv = wr[c];
            ps += wv * ar[c];
            pd += wv * dr[c];
        }
    }
    Ps[idx] = ps;
    Pd[idx] = pd;
}

// ---------------- zero h1 split pad rows (read as GEMM2 A-operand) ---------

__global__ __launch_bounds__(256) void zeropads_k(u16* __restrict__ h1hi, u16* __restrict__ h1lo,
                                                  int Nn) {
    int tot = (MPAD - Nn) * 448;
    int idx = blockIdx.x * 256 + threadIdx.x;
    if (idx < tot) {
        h1hi[(size_t)Nn * 448 + idx] = 0;
        h1lo[(size_t)Nn * 448 + idx] = 0;
    }
}

// ---------------- layer-1 alphas: (x @ P1), K=129, wave per node -----------

__global__ __launch_bounds__(256) void alpha1_k(const float* __restrict__ x,
                                                const float* __restrict__ Ps,
                                                const float* __restrict__ Pd,
                                                float* __restrict__ oS, float* __restrict__ oD, int n) {
    int wv = threadIdx.x >> 6, lane = threadIdx.x & 63;
    int i = blockIdx.x * 4 + wv;
    if (i >= n) return;
    const float* row = x + (size_t)i * NFEAT;
    float x0 = row[lane], x1 = row[64 + lane];
    float ps[8], pd[8];
    #pragma unroll
    for (int h = 0; h < 8; ++h) {
        ps[h] = x0 * Ps[lane * 8 + h] + x1 * Ps[(64 + lane) * 8 + h];
        pd[h] = x0 * Pd[lane * 8 + h] + x1 * Pd[(64 + lane) * 8 + h];
    }
    if (lane == 0) {
        float x2 = row[128];
        #pragma unroll
        for (int h = 0; h < 8; ++h) {
            ps[h] += x2 * Ps[128 * 8 + h];
            pd[h] += x2 * Pd[128 * 8 + h];
        }
    }
    #pragma unroll
    for (int h = 0; h < 8; ++h) {
        #pragma unroll
        for (int off = 32; off; off >>= 1) {
            ps[h] += __shfl_xor(ps[h], off);
            pd[h] += __shfl_xor(pd[h], off);
        }
    }
    if (lane == 0) {
        #pragma unroll
        for (int h = 0; h < 8; ++h) {
            oS[(size_t)i * 8 + h] = ps[h];
            oD[(size_t)i * 8 + h] = pd[h];
        }
    }
}

// ---------------- LDS swizzle helper ----------------

__device__ __forceinline__ int swz(int r, int s) {
    return (r << 2) | ((s ^ (r & 3) ^ ((r >> 2) & 3)) & 3);
}

// ---------------- split MFMA GEMM, fp16 output: C16 = A @ Wt^T -------------
// Tile 128x128, BK=32, 4 waves (2m x 2n), 3 MFMAs per hi/lo pair.

__global__ __launch_bounds__(256) void gemm16(
    const u16* __restrict__ Ahi, const u16* __restrict__ Alo,
    const u16* __restrict__ Bhi, const u16* __restrict__ Blo,
    u16* __restrict__ C16, int M, int Ncols, int Kp)
{
    __shared__ __align__(16) u16 sAh[128 * 32];
    __shared__ __align__(16) u16 sAl[128 * 32];
    __shared__ __align__(16) u16 sBh[128 * 32];
    __shared__ __align__(16) u16 sBl[128 * 32];
    const int tid = threadIdx.x;
    const int m0 = blockIdx.y * 128;
    const int n0 = blockIdx.x * 128;
    const int lane = tid & 63, wave = tid >> 6;
    const int wm = wave >> 1, wn = wave & 1;
    const int l15 = lane & 15, lg = lane >> 4;
    const int r0 = tid >> 2, s0 = tid & 3;
    const int w0 = swz(r0, s0), w1 = swz(r0 + 64, s0);
    f32x4 acc[4][4] = {};

    for (int k0 = 0; k0 < Kp; k0 += 32) {
        size_t gA0 = (size_t)(m0 + r0) * Kp + k0 + s0 * 8;
        size_t gA1 = (size_t)(m0 + r0 + 64) * Kp + k0 + s0 * 8;
        size_t gB0 = (size_t)(n0 + r0) * Kp + k0 + s0 * 8;
        size_t gB1 = (size_t)(n0 + r0 + 64) * Kp + k0 + s0 * 8;
        short8v ah0 = *(const short8v*)(Ahi + gA0);
        short8v ah1 = *(const short8v*)(Ahi + gA1);
        short8v al0 = *(const short8v*)(Alo + gA0);
        short8v al1 = *(const short8v*)(Alo + gA1);
        short8v bh0 = *(const short8v*)(Bhi + gB0);
        short8v bh1 = *(const short8v*)(Bhi + gB1);
        short8v bl0 = *(const short8v*)(Blo + gB0);
        short8v bl1 = *(const short8v*)(Blo + gB1);
        __syncthreads();
        ((short8v*)sAh)[w0] = ah0; ((short8v*)sAh)[w1] = ah1;
        ((short8v*)sAl)[w0] = al0; ((short8v*)sAl)[w1] = al1;
        ((short8v*)sBh)[w0] = bh0; ((short8v*)sBh)[w1] = bh1;
        ((short8v*)sBl)[w0] = bl0; ((short8v*)sBl)[w1] = bl1;
        __syncthreads();
        FragU fah[4], fal[4], fbh[4], fbl[4];
        #pragma unroll
        for (int mf = 0; mf < 4; ++mf) {
            int rr = wm * 64 + mf * 16 + l15;
            int idx = swz(rr, lg);
            fah[mf].s = ((const short8v*)sAh)[idx];
            fal[mf].s = ((const short8v*)sAl)[idx];
        }
        #pragma unroll
        for (int nf = 0; nf < 4; ++nf) {
            int rr = wn * 64 + nf * 16 + l15;
            int idx = swz(rr, lg);
            fbh[nf].s = ((const short8v*)sBh)[idx];
            fbl[nf].s = ((const short8v*)sBl)[idx];
        }
        #pragma unroll
        for (int mf = 0; mf < 4; ++mf) {
            #pragma unroll
            for (int nf = 0; nf < 4; ++nf) {
                acc[mf][nf] = __builtin_amdgcn_mfma_f32_16x16x32_bf16(fah[mf].b, fbh[nf].b, acc[mf][nf], 0, 0, 0);
                acc[mf][nf] = __builtin_amdgcn_mfma_f32_16x16x32_bf16(fah[mf].b, fbl[nf].b, acc[mf][nf], 0, 0, 0);
                acc[mf][nf] = __builtin_amdgcn_mfma_f32_16x16x32_bf16(fal[mf].b, fbh[nf].b, acc[mf][nf], 0, 0, 0);
            }
        }
    }
    #pragma unroll
    for (int mf = 0; mf < 4; ++mf) {
        #pragma unroll
        for (int nf = 0; nf < 4; ++nf) {
            int colg = n0 + wn * 64 + nf * 16 + l15;
            if (colg >= Ncols) continue;
            #pragma unroll
            for (int r = 0; r < 4; ++r) {
                int rowg = m0 + wm * 64 + mf * 16 + lg * 4 + r;
                if (rowg < M) C16[(size_t)rowg * Ncols + colg] = f2h(acc[mf][nf][r]);
            }
        }
    }
}

// ---------------- fused agg: weights+denom inline, fp16 gather, proj epi ---
// wave per node; lane owns 8 consecutive channels (16B fp16 load/edge);
// 4 edges in flight; edges arrive CLUSTERED BY SRC BLOCK (CSR key order).

template <int H, int C, bool RELU, bool SPLIT, bool PROJ>
__global__ __launch_bounds__(256) void aggF_k(
    const u16* __restrict__ hf,                                  // fp16 h~ [n][HC]
    const float* __restrict__ as_, const float* __restrict__ ad_,
    const float* __restrict__ bias,
    const int* __restrict__ row_ptr,                             // keyed: [n*KPD+1]
    const int* __restrict__ col,
    const float* __restrict__ Pns, const float* __restrict__ Pnd, // next-layer proj [HC][8]
    float* __restrict__ nas, float* __restrict__ nad,             // next-layer alphas
    float* __restrict__ outf, u16* __restrict__ ohi, u16* __restrict__ olo,
    int n)
{
    constexpr int HC = H * C;
    constexpr int LACT = HC / 8;
    const int wv = threadIdx.x >> 6, lane = threadIdx.x & 63;
    const int i = blockIdx.x * 4 + wv;
    if (i >= n) return;
    const int ch0 = lane * 8;
    const bool act = lane < LACT;
    const int h = act ? (ch0 / C) : 0;
    const bool lead = act && ((ch0 % C) == 0);
    const int beg = row_ptr[i * KPD], end = row_ptr[(i + 1) * KPD];
    float acc[8] = {};
    float dp = 0.f;
    if (act) {
        const float adh = ad_[(size_t)i * 8 + h];
        int e = beg;
        for (; e + 4 <= end; e += 4) {
            int sA = col[e],     sB = col[e + 1];
            int sC = col[e + 2], sD = col[e + 3];
            float fA = as_[(size_t)sA * 8 + h] + adh;
            float fB = as_[(size_t)sB * 8 + h] + adh;
            float fC = as_[(size_t)sC * 8 + h] + adh;
            float fD = as_[(size_t)sD * 8 + h] + adh;
            u16x8 vA = *(const u16x8*)(hf + (size_t)sA * HC + ch0);
            u16x8 vB = *(const u16x8*)(hf + (size_t)sB * HC + ch0);
            u16x8 vC = *(const u16x8*)(hf + (size_t)sC * HC + ch0);
            u16x8 vD = *(const u16x8*)(hf + (size_t)sD * HC + ch0);
            fA = fA > 0.f ? fA : 0.2f * fA;
            fB = fB > 0.f ? fB : 0.2f * fB;
            fC = fC > 0.f ? fC : 0.2f * fC;
            fD = fD > 0.f ? fD : 0.2f * fD;
            float wA = __expf(fA), wB = __expf(fB);
            float wC = __expf(fC), wD = __expf(fD);
            #pragma unroll
            for (int j = 0; j < 8; ++j)
                acc[j] += wA * h2f(vA[j]) + wB * h2f(vB[j])
                        + wC * h2f(vC[j]) + wD * h2f(vD[j]);
            if (lead) dp += (wA + wB) + (wC + wD);
        }
        for (; e + 2 <= end; e += 2) {
            int sA = col[e], sB = col[e + 1];
            float fA = as_[(size_t)sA * 8 + h] + adh;
            float fB = as_[(size_t)sB * 8 + h] + adh;
            u16x8 vA = *(const u16x8*)(hf + (size_t)sA * HC + ch0);
            u16x8 vB = *(const u16x8*)(hf + (size_t)sB * HC + ch0);
            fA = fA > 0.f ? fA : 0.2f * fA;
            fB = fB > 0.f ? fB : 0.2f * fB;
            float wA = __expf(fA), wB = __expf(fB);
            #pragma unroll
            for (int j = 0; j < 8; ++j)
                acc[j] += wA * h2f(vA[j]) + wB * h2f(vB[j]);
            if (lead) dp += wA + wB;
        }
        if (e < end) {
            int sA = col[e];
            float fA = as_[(size_t)sA * 8 + h] + adh;
            u16x8 vA = *(const u16x8*)(hf + (size_t)sA * HC + ch0);
            fA = fA > 0.f ? fA : 0.2f * fA;
            float wA = __expf(fA);
            #pragma unroll
            for (int j = 0; j < 8; ++j)
                acc[j] += wA * h2f(vA[j]);
            if (lead) dp += wA;
        }
    }
    const float den = __shfl(dp, h * (C / 8)) + 1e-16f;
    float o[8];
    #pragma unroll
    for (int j = 0; j < 8; ++j) o[j] = 0.f;
    if (act) {
        #pragma unroll
        for (int j = 0; j < 8; ++j) {
            float v = acc[j] / den + bias[ch0 + j];
            if (RELU) v = fmaxf(v, 0.f);
            o[j] = v;
        }
        size_t base = (size_t)i * HC + ch0;
        if constexpr (SPLIT) {
            u16x8 ph, pl;
            #pragma unroll
            for (int j = 0; j < 8; ++j) {
                u16 hi = f2bf(o[j]);
                ph[j] = hi;
                pl[j] = f2bf(o[j] - bf2f(hi));
            }
            *(u16x8*)(ohi + base) = ph;
            *(u16x8*)(olo + base) = pl;
        } else {
            float4 q0; q0.x = o[0]; q0.y = o[1]; q0.z = o[2]; q0.w = o[3];
            float4 q1; q1.x = o[4]; q1.y = o[5]; q1.z = o[6]; q1.w = o[7];
            *(float4*)(outf + base) = q0;
            *(float4*)(outf + base + 4) = q1;
        }
    }
    if constexpr (PROJ) {
        float ps[8] = {}, pd[8] = {};
        if (act) {
            #pragma unroll
            for (int j = 0; j < 8; ++j) {
                const float* prs = Pns + (size_t)(ch0 + j) * 8;
                const float* prd = Pnd + (size_t)(ch0 + j) * 8;
                #pragma unroll
                for (int hp = 0; hp < 8; ++hp) {
                    ps[hp] += o[j] * prs[hp];
                    pd[hp] += o[j] * prd[hp];
                }
            }
        }
        #pragma unroll
        for (int hp = 0; hp < 8; ++hp) {
            #pragma unroll
            for (int off = 32; off; off >>= 1) {
                ps[hp] += __shfl_xor(ps[hp], off);
                pd[hp] += __shfl_xor(pd[hp], off);
            }
        }
        if (lane == 0) {
            #pragma unroll
            for (int hp = 0; hp < 8; ++hp) {
                nas[(size_t)i * 8 + hp] = ps[hp];
                nad[(size_t)i * 8 + hp] = pd[hp];
            }
        }
    }
}

// ---------------------------------------------------------------------------

extern "C" void kernel_launch(void* const* d_in, const int* in_sizes, int n_in,
                              void* d_out, int out_size, void* d_ws, size_t ws_size,
                              hipStream_t stream) {
    const float* x   = (const float*)d_in[0];
    const int*   ei  = (const int*)d_in[1];
    const float* W1  = (const float*)d_in[2];
    const float* a1s = (const float*)d_in[3];
    const float* a1d = (const float*)d_in[4];
    const float* b1  = (const float*)d_in[5];
    const float* W2  = (const float*)d_in[6];
    const float* a2s = (const float*)d_in[7];
    const float* a2d = (const float*)d_in[8];
    const float* b2  = (const float*)d_in[9];
    const float* W3  = (const float*)d_in[10];
    const float* a3s = (const float*)d_in[11];
    const float* a3d = (const float*)d_in[12];
    const float* b3  = (const float*)d_in[13];
    float* out = (float*)d_out;

    const int Nn = in_sizes[0] / NFEAT;   // 30000
    const int E  = in_sizes[1] / 2;       // 480000
    const int Et = E + Nn;
    const int NK = Nn * KPD;              // 480000 keys
    const int NB = (NK + 255) / 256;      // 1875 scan blocks
    const int* srcp = ei;
    const int* dstp = ei + E;

    char* ws = (char*)d_ws;
    size_t off = 0;
    auto carve = [&](size_t bytes) -> char* {
        char* p = ws + off;
        off += (bytes + 255) & ~(size_t)255;
        return p;
    };
    u16*   hbuf16 = (u16*)carve((size_t)MPAD * 448 * 2);   // h~ fp16 (all layers)
    u16*   h1hi  = (u16*)carve((size_t)MPAD * 448 * 2);    // h split
    u16*   h1lo  = (u16*)carve((size_t)MPAD * 448 * 2);
    u16*   Xhi   = (u16*)carve((size_t)MPAD * 160 * 2);
    u16*   Xlo   = (u16*)carve((size_t)MPAD * 160 * 2);
    u16*   Wthi  = (u16*)carve((size_t)352256 * 2);
    u16*   Wtlo  = (u16*)carve((size_t)352256 * 2);
    int*   col   = (int*)carve((size_t)Et * 4);
    int* row_ptr = (int*)carve((size_t)(NK + 1) * 4);
    int*   cnt   = (int*)carve((size_t)NK * 4);
    int*   bsum  = (int*)carve((size_t)NB * 4);
    int*   bofs  = (int*)carve((size_t)(NB + 1) * 4);
    float* aA    = (float*)carve((size_t)Nn * 8 * 4);
    float* dA    = (float*)carve((size_t)Nn * 8 * 4);
    float* aB    = (float*)carve((size_t)Nn * 8 * 4);
    float* dB    = (float*)carve((size_t)Nn * 8 * 4);
    float* Ps    = (float*)carve((size_t)992 * 8 * 4);
    float* Pd    = (float*)carve((size_t)992 * 8 * 4);
    (void)ws_size;

    const int nb4 = (Nn + 3) / 4;   // 7500
    const int mg  = MPAD / 128;     // 235

    // ---- CSR keyed by (dst, src-block): edge lists come out block-clustered --
    hipMemsetAsync(cnt, 0, (size_t)NK * 4, stream);
    hist_k<<<(Et + 255) / 256, 256, 0, stream>>>(srcp, dstp, cnt, E, Nn);
    bsum_k<<<NB, 256, 0, stream>>>(cnt, bsum, NK);
    bscan_k<<<1, 1024, 0, stream>>>(bsum, bofs, NB);
    scanw_k<<<NB, 256, 0, stream>>>(cnt, bofs, row_ptr, NK);
    hipMemsetAsync(cnt, 0, (size_t)NK * 4, stream);
    scatter_k<<<(Et + 255) / 256, 256, 0, stream>>>(srcp, dstp, row_ptr, cnt, col, E, Nn);

    // ---- input prep (independent of CSR) ----
    xsplit_k<<<((MPAD * 160) + 255) / 256, 256, 0, stream>>>(x, Xhi, Xlo, Nn, NFEAT, 160, MPAD);
    wsplitAll_k<<<(352256 + 255) / 256, 256, 0, stream>>>(W1, W2, W3, Wthi, Wtlo);
    projAll_k<<<(992 * 8 + 255) / 256, 256, 0, stream>>>(W1, a1s, a1d, W2, a2s, a2d, W3, a3s, a3d, Ps, Pd);
    zeropads_k<<<(((MPAD - Nn) * 448) + 255) / 256, 256, 0, stream>>>(h1hi, h1lo, Nn);

    // ---- layer 1: x(129) -> 7x64 ----
    alpha1_k<<<nb4, 256, 0, stream>>>(x, Ps, Pd, aA, dA, Nn);
    gemm16<<<dim3(4, mg), 256, 0, stream>>>(Xhi, Xlo, Wthi, Wtlo, hbuf16, Nn, 448, 160);
    aggF_k<7, 64, true, true, true><<<nb4, 256, 0, stream>>>(
        hbuf16, aA, dA, b1, row_ptr, col, Ps + 1280, Pd + 1280, aB, dB,
        nullptr, h1hi, h1lo, Nn);

    // ---- layer 2: 448 -> 6x64 ----
    gemm16<<<dim3(3, mg), 256, 0, stream>>>(h1hi, h1lo, Wthi + 81920, Wtlo + 81920, hbuf16, Nn, 384, 448);
    aggF_k<6, 64, true, true, true><<<nb4, 256, 0, stream>>>(
        hbuf16, aB, dB, b2, row_ptr, col, Ps + 4864, Pd + 4864, aA, dA,
        nullptr, h1hi, h1lo, Nn);

    // ---- layer 3: 384 -> 6x40 ----
    gemm16<<<dim3(2, mg), 256, 0, stream>>>(h1hi, h1lo, Wthi + 253952, Wtlo + 253952, hbuf16, Nn, 240, 384);
    aggF_k<6, 40, false, false, false><<<nb4, 256, 0, stream>>>(
        hbuf16, aA, dA, b3, row_ptr, col, nullptr, nullptr, nullptr, nullptr,
        out, nullptr, nullptr, Nn);
}